// Round 14
// baseline (549.756 us; speedup 1.0000x reference)
//
#include <hip/hip_runtime.h>
#include <math.h>

#define B_ 64
#define M_ 1024
#define H_ 64
#define N_ (B_*M_)   // 65536

typedef _Float16 half8 __attribute__((ext_vector_type(8)));
typedef float  floatx4 __attribute__((ext_vector_type(4)));

#define MFMA16(a,b,c) __builtin_amdgcn_mfma_f32_16x16x32_f16(a,b,c,0,0,0)
#define MED3(a,b,c)   __builtin_amdgcn_fmed3f(a,b,c)

// ---- encoder (+ fused A1 = h @ W1b of ec1): hhi/hlo/sq/A ----
__global__ __launch_bounds__(256) void enc_kernel(
    const float* __restrict__ x,     // [N,4]
    const float* __restrict__ w1,    // [4,32]
    const float* __restrict__ b1,    // [32]
    const float* __restrict__ w2,    // [32,64]
    const float* __restrict__ b2,    // [64]
    const float* __restrict__ ecw1,  // [128,64] (layer-1 edge W1; rows 64.. = W1b)
    _Float16* __restrict__ hhi,      // [N,64]
    _Float16* __restrict__ hlo,      // [N,64]
    float* __restrict__ sq,          // [N]
    float* __restrict__ A)           // [N,64]
{
    __shared__ float sw1[4*32];
    __shared__ float sb1[32];
    __shared__ float sw2[32*64];
    __shared__ float sb2[64];
    __shared__ float swb[64*64];
    int t = threadIdx.x;
    for (int i = t; i < 128; i += 256) sw1[i] = w1[i];
    if (t < 32) sb1[t] = b1[t];
    for (int i = t; i < 2048; i += 256) sw2[i] = w2[i];
    if (t < 64) sb2[t] = b2[t];
    for (int i = t; i < 4096; i += 256) swb[i] = ecw1[4096 + i];
    __syncthreads();
    int n = blockIdx.x * 256 + t;
    float4 xv = *(const float4*)(x + (size_t)n*4);
    float hid[32];
    #pragma unroll
    for (int o = 0; o < 32; ++o) {
        float a = sb1[o] + xv.x*sw1[0*32+o] + xv.y*sw1[1*32+o]
                        + xv.z*sw1[2*32+o] + xv.w*sw1[3*32+o];
        hid[o] = fmaxf(a, 0.f);
    }
    float4 hv[16];
    float sqa = 0.f;
    #pragma unroll 4
    for (int oc = 0; oc < 16; ++oc) {
        float4 acc = make_float4(sb2[oc*4+0], sb2[oc*4+1], sb2[oc*4+2], sb2[oc*4+3]);
        #pragma unroll
        for (int f = 0; f < 32; ++f) {
            float4 w = *(const float4*)(sw2 + f*64 + oc*4);
            float hv_ = hid[f];
            acc.x += hv_*w.x; acc.y += hv_*w.y; acc.z += hv_*w.z; acc.w += hv_*w.w;
        }
        acc.x = fmaxf(acc.x,0.f); acc.y = fmaxf(acc.y,0.f);
        acc.z = fmaxf(acc.z,0.f); acc.w = fmaxf(acc.w,0.f);
        hv[oc] = acc;
        sqa += acc.x*acc.x + acc.y*acc.y + acc.z*acc.z + acc.w*acc.w;
        union { _Float16 f[4]; uint2 u; } Hh, Hl;
        Hh.f[0]=(_Float16)acc.x; Hh.f[1]=(_Float16)acc.y;
        Hh.f[2]=(_Float16)acc.z; Hh.f[3]=(_Float16)acc.w;
        Hl.f[0]=(_Float16)(acc.x-(float)Hh.f[0]); Hl.f[1]=(_Float16)(acc.y-(float)Hh.f[1]);
        Hl.f[2]=(_Float16)(acc.z-(float)Hh.f[2]); Hl.f[3]=(_Float16)(acc.w-(float)Hh.f[3]);
        *(uint2*)(hhi + (size_t)n*64 + oc*4) = Hh.u;
        *(uint2*)(hlo + (size_t)n*64 + oc*4) = Hl.u;
    }
    sq[n] = sqa;
    float* dst = A + (size_t)n*64;
    #pragma unroll 2
    for (int oc = 0; oc < 16; ++oc) {
        float4 acc = make_float4(0.f,0.f,0.f,0.f);
        #pragma unroll
        for (int f = 0; f < 64; ++f) {
            float xf = ((const float*)hv)[f];
            float4 w = *(const float4*)(swb + f*64 + oc*4);
            acc.x += xf*w.x; acc.y += xf*w.y; acc.z += xf*w.z; acc.w += xf*w.w;
        }
        *(float4*)(dst + oc*4) = acc;
    }
}

// ---- prep2 (layer-2): thread-per-node, sq + A = h @ W1b from hhi/hlo ----
__global__ __launch_bounds__(256) void prep2_kernel(
    const _Float16* __restrict__ hhi,
    const _Float16* __restrict__ hlo,
    const float* __restrict__ ecw1,  // [128,64] (layer-2 edge W1)
    float* __restrict__ A,
    float* __restrict__ sq)
{
    __shared__ float swb[64*64];
    int t = threadIdx.x;
    for (int i = t; i < 4096; i += 256) swb[i] = ecw1[4096 + i];
    __syncthreads();
    int n = blockIdx.x * 256 + t;
    float hv[64];
    const _Float16* sh = hhi + (size_t)n*64;
    const _Float16* sl = hlo + (size_t)n*64;
    float sqa = 0.f;
    #pragma unroll
    for (int c = 0; c < 8; ++c) {
        half8 a = *(const half8*)(sh + c*8);
        half8 b = *(const half8*)(sl + c*8);
        #pragma unroll
        for (int j = 0; j < 8; ++j) {
            float v = (float)a[j] + (float)b[j];
            hv[c*8+j] = v;
            sqa += v*v;
        }
    }
    sq[n] = sqa;
    float* dst = A + (size_t)n*64;
    #pragma unroll 2
    for (int oc = 0; oc < 16; ++oc) {
        float4 acc = make_float4(0.f,0.f,0.f,0.f);
        #pragma unroll
        for (int f = 0; f < 64; ++f) {
            float xf = hv[f];
            float4 w = *(const float4*)(swb + f*64 + oc*4);
            acc.x += xf*w.x; acc.y += xf*w.y; acc.z += xf*w.z; acc.w += xf*w.w;
        }
        *(float4*)(dst + oc*4) = acc;
    }
}

// ---- kNN v12: register-direct keys (A=cands, B=queries), no D LDS, bitonic merge -
// Wave w owns queries qt*64 + w*16 + m16; streams all 64 candidate 16-tiles.
// D[c][q]: lane (gid,m16) holds cands gid*4+r for query m16 -> insert from regs.
// Keys bit-identical to R13 (same products, same (1+sq_q)+sq_c init order).
__global__ __launch_bounds__(256) void knn_kernel(
    const _Float16* __restrict__ hhi,
    const _Float16* __restrict__ hlo,
    const float* __restrict__ sqg,
    unsigned short* __restrict__ knn)    // [N,16]
{
    __shared__ float sqS[1024];
    int t = threadIdx.x, lane = t & 63, w = t >> 6;
    int bi = blockIdx.x;
    int g  = (bi & 7) | ((bi >> 7) << 3);  // 16 blocks/graph share bi%8 -> same XCD L2
    int qt = (bi >> 3) & 15;
    const _Float16* hhig = hhi + (size_t)g*M_*64;
    const _Float16* hlog = hlo + (size_t)g*M_*64;
    const float*    sqb  = sqg + (size_t)g*M_;
    ((float4*)sqS)[t] = ((const float4*)sqb)[t];   // 4 KB

    int m16 = lane & 15;
    int gid = lane >> 4;
    int koct = gid * 8;
    int qloc = qt*64 + w*16 + m16;        // this lane's query (local id)

    // B-frags = this wave's queries, scaled by -2 (exact in f16)
    half8 Bqh[2], Bql[2];
    {
        const _Float16* qh = hhig + (size_t)qloc*64;
        const _Float16* ql = hlog + (size_t)qloc*64;
        Bqh[0] = *(const half8*)(qh + koct);
        Bqh[1] = *(const half8*)(qh + 32 + koct);
        Bql[0] = *(const half8*)(ql + koct);
        Bql[1] = *(const half8*)(ql + 32 + koct);
        #pragma unroll
        for (int p = 0; p < 2; ++p)
            #pragma unroll
            for (int j = 0; j < 8; ++j) {
                Bqh[p][j] = Bqh[p][j] * (_Float16)-2.0f;
                Bql[p][j] = Bql[p][j] * (_Float16)-2.0f;
            }
    }
    __syncthreads();                      // sqS ready (only barrier)
    float c1q = 1.f + sqS[qloc];

    float bd[16];
    #pragma unroll
    for (int k = 0; k < 16; ++k) bd[k] = INFINITY;

    #pragma unroll 4
    for (int ct = 0; ct < 64; ++ct) {     // 64 candidate tiles of 16
        int c0 = ct*16;
        const _Float16* ph = hhig + (size_t)(c0 + m16)*64;
        const _Float16* pl = hlog + (size_t)(c0 + m16)*64;
        half8 Ah0 = *(const half8*)(ph + koct);
        half8 Ah1 = *(const half8*)(ph + 32 + koct);
        half8 Al0 = *(const half8*)(pl + koct);
        half8 Al1 = *(const half8*)(pl + 32 + koct);
        float4 sqc = *(const float4*)(sqS + c0 + gid*4);
        floatx4 acc = {c1q + sqc.x, c1q + sqc.y, c1q + sqc.z, c1q + sqc.w};
        acc = MFMA16(Ah0, Bqh[0], acc);
        acc = MFMA16(Ah1, Bqh[1], acc);
        acc = MFMA16(Ah0, Bql[0], acc);
        acc = MFMA16(Ah1, Bql[1], acc);
        acc = MFMA16(Al0, Bqh[0], acc);
        acc = MFMA16(Al1, Bqh[1], acc);
        #pragma unroll
        for (int r = 0; r < 4; ++r) {
            int cand = c0 + gid*4 + r;
            unsigned kb = (__float_as_uint(acc[r]) & 0xFFFFFC00u) | (unsigned)cand;
            float fk = __uint_as_float(kb);
            if (cand == qloc) fk = INFINITY;
            float nb0 = fminf(bd[0], fk);
            #pragma unroll
            for (int k = 15; k >= 1; --k) bd[k] = MED3(fk, bd[k-1], bd[k]);
            bd[0] = nb0;
        }
    }

    // ---- bitonic min-merge of the 4 gid-partial sorted lists (xor 16, then 32) --
    #pragma unroll
    for (int X = 16; X <= 32; X <<= 1) {
        float nb[16];
        #pragma unroll
        for (int k = 0; k < 16; ++k) {
            float ov = __shfl_xor(bd[15-k], X, 64);
            nb[k] = fminf(bd[k], ov);
        }
        // nb is bitonic; sort ascending (bitonic merge network)
        #pragma unroll
        for (int d = 8; d >= 1; d >>= 1) {
            #pragma unroll
            for (int i = 0; i < 16; ++i) {
                if (!(i & d)) {
                    float lo = fminf(nb[i], nb[i+d]);
                    float hi = fmaxf(nb[i], nb[i+d]);
                    nb[i] = lo; nb[i+d] = hi;
                }
            }
        }
        #pragma unroll
        for (int k = 0; k < 16; ++k) bd[k] = nb[k];
    }

    if (lane < 16) {                      // gid==0 lanes write their query
        union { unsigned short us[16]; uint4 v4[2]; } o;
        #pragma unroll
        for (int k = 0; k < 16; ++k)
            o.us[k] = (unsigned short)(__float_as_uint(bd[k]) & 1023u);
        size_t gq = (size_t)g*M_ + qt*64 + w*16 + lane;
        uint4* dst = (uint4*)(knn + gq*16);
        dst[0] = o.v4[0];
        dst[1] = o.v4[1];
    }
}

// ---- EdgeConv v5 (MFMA): f16 state in/out, batched neighbor-index prefetch ----
__global__ __launch_bounds__(256) void edge_kernel(
    _Float16* __restrict__ hhi,      // [N,64] in/out (own rows read before written)
    _Float16* __restrict__ hlo,      // [N,64] in/out
    const float* __restrict__ A,     // [N,64]
    const unsigned short* __restrict__ knn, // [N,16] local idx
    const float* __restrict__ w1,    // [128,64]
    const float* __restrict__ b1,    // [64]
    const float* __restrict__ w2,    // [64,64]
    const float* __restrict__ b2)    // [64]
{
    __shared__ __align__(16) _Float16 wdf[16*64*8];   // Wd B-frags (16 KB)
    __shared__ __align__(16) _Float16 w2f[16*64*8];   // W2 B-frags (16 KB) -> Cs after
    float* CsB = (float*)w2f;                          // Cs[4][16][64] alias (16 KB)
    int t = threadIdx.x;
    for (int u = t; u < 512; u += 256) {
        int ulane = u & 63, nt = u >> 7, ks = (u >> 6) & 1;
        int n = nt*16 + (ulane & 15);
        int kbase = ks*32 + ((ulane >> 4) * 8);
        int fh = (((nt*2+ks)*2+0)*64 + ulane)*8;
        int fl = (((nt*2+ks)*2+1)*64 + ulane)*8;
        #pragma unroll
        for (int j = 0; j < 8; ++j) {
            int k = kbase + j;
            float vd = w1[k*64+n] - w1[4096 + k*64+n];
            _Float16 dh = (_Float16)vd;
            wdf[fh+j] = dh;
            wdf[fl+j] = (_Float16)(vd - (float)dh);
            float v2 = w2[k*64+n];
            _Float16 h2 = (_Float16)v2;
            w2f[fh+j] = h2;
            w2f[fl+j] = (_Float16)(v2 - (float)h2);
        }
    }
    __syncthreads();
    int lane = t & 63, wid = t >> 6;
    int m16 = lane & 15, gid = lane >> 4;
    int koct = gid*8, crow = gid*4;
    int bi = blockIdx.x;
    int g  = (bi & 7) | ((bi >> 7) << 3);    // XCD swizzle
    int qt = (bi >> 3) & 15;
    int i0 = g*M_ + qt*64 + wid*16;          // first node of this wave
    const float* Ab = A + (size_t)g*M_*H_;

    half8 W2r[4][2][2];
    #pragma unroll
    for (int nt = 0; nt < 4; ++nt)
        #pragma unroll
        for (int ks = 0; ks < 2; ++ks)
            #pragma unroll
            for (int p = 0; p < 2; ++p)
                W2r[nt][ks][p] = *(const half8*)&w2f[(((nt*2+ks)*2+p)*64+lane)*8];

    float b1v[4];
    #pragma unroll
    for (int nt = 0; nt < 4; ++nt) b1v[nt] = b1[nt*16+m16];
    float b2v = b2[gid*16+m16];
    __syncthreads();   // all waves done reading w2f -> safe to overwrite with Cs

    // ---- Phase 1: C tile = h(16 nodes) @ Wd + b1 -> CsB (direct f16 loads) ----
    half8 Hh[2], Hl[2];
    #pragma unroll
    for (int ks = 0; ks < 2; ++ks) {
        Hh[ks] = *(const half8*)(hhi + (size_t)(i0+m16)*64 + ks*32 + koct);
        Hl[ks] = *(const half8*)(hlo + (size_t)(i0+m16)*64 + ks*32 + koct);
    }
    // batched neighbor-index prefetch (breaks load->gather dependence)
    const unsigned short* knb = knn + (size_t)i0*16;
    int kidx[16];
    #pragma unroll
    for (int nn = 0; nn < 16; ++nn) kidx[nn] = knb[nn*16 + m16];

    #pragma unroll
    for (int nt = 0; nt < 4; ++nt) {
        floatx4 acc = {b1v[nt], b1v[nt], b1v[nt], b1v[nt]};
        #pragma unroll
        for (int ks = 0; ks < 2; ++ks) {
            half8 wh = *(const half8*)&wdf[(((nt*2+ks)*2+0)*64+lane)*8];
            half8 wl = *(const half8*)&wdf[(((nt*2+ks)*2+1)*64+lane)*8];
            acc = MFMA16(Hh[ks], wh, acc);
            acc = MFMA16(Hh[ks], wl, acc);
            acc = MFMA16(Hl[ks], wh, acc);
        }
        #pragma unroll
        for (int r = 0; r < 4; ++r)
            CsB[((wid*16) + crow + r)*64 + nt*16 + m16] = acc[r];
    }
    __syncthreads();

    // ---- Phase 2: per node, msg = relu(C + A_j), out = max_e msg@W2 + b2 ----
    #pragma unroll 2
    for (int nn = 0; nn < 16; ++nn) {
        const float* Ap = Ab + (size_t)kidx[nn]*64;
        half8 Mh[2], Ml[2];
        #pragma unroll
        for (int ks = 0; ks < 2; ++ks) {
            float4 a0 = *(const float4*)(Ap + ks*32 + koct);
            float4 a1 = *(const float4*)(Ap + ks*32 + koct + 4);
            const float* cp = &CsB[(wid*16 + nn)*64 + ks*32 + koct];
            float4 c0 = *(const float4*)cp;
            float4 c1 = *(const float4*)(cp+4);
            float mv[8] = {
                fmaxf(a0.x+c0.x,0.f), fmaxf(a0.y+c0.y,0.f),
                fmaxf(a0.z+c0.z,0.f), fmaxf(a0.w+c0.w,0.f),
                fmaxf(a1.x+c1.x,0.f), fmaxf(a1.y+c1.y,0.f),
                fmaxf(a1.z+c1.z,0.f), fmaxf(a1.w+c1.w,0.f)};
            #pragma unroll
            for (int jj = 0; jj < 8; ++jj) {
                _Float16 hi = (_Float16)mv[jj];
                Mh[ks][jj] = hi;
                Ml[ks][jj] = (_Float16)(mv[jj]-(float)hi);
            }
        }
        floatx4 acc[4];
        #pragma unroll
        for (int nt = 0; nt < 4; ++nt) {
            acc[nt] = (floatx4){0.f,0.f,0.f,0.f};
            #pragma unroll
            for (int ks = 0; ks < 2; ++ks) {
                acc[nt] = MFMA16(Mh[ks], W2r[nt][ks][0], acc[nt]);
                acc[nt] = MFMA16(Mh[ks], W2r[nt][ks][1], acc[nt]);
                acc[nt] = MFMA16(Ml[ks], W2r[nt][ks][0], acc[nt]);
            }
        }
        float om[4];
        #pragma unroll
        for (int nt = 0; nt < 4; ++nt) {
            float mr = fmaxf(fmaxf(acc[nt][0], acc[nt][1]),
                             fmaxf(acc[nt][2], acc[nt][3]));
            mr = fmaxf(mr, __shfl_xor(mr, 16, 64));
            mr = fmaxf(mr, __shfl_xor(mr, 32, 64));
            om[nt] = mr;
        }
        float val = (gid == 0) ? om[0] : (gid == 1) ? om[1]
                  : (gid == 2) ? om[2] : om[3];
        float ov = val + b2v;                      // h_out[i0+nn][lane]
        _Float16 oh = (_Float16)ov;
        _Float16 ol = (_Float16)(ov - (float)oh);
        hhi[(size_t)(i0+nn)*64 + lane] = oh;
        hlo[(size_t)(i0+nn)*64 + lane] = ol;
    }
}

// ---- mean-pool + output MLP (reads hhi+hlo) ----
__global__ __launch_bounds__(256) void pool_kernel(
    const _Float16* __restrict__ hhi,
    const _Float16* __restrict__ hlo,
    const float* __restrict__ w1,   // [64,32]
    const float* __restrict__ b1,   // [32]
    const float* __restrict__ w2,   // [32,1]
    const float* __restrict__ b2,   // [1]
    float* __restrict__ out)        // [B]
{
    __shared__ float part[4][64];
    __shared__ float g[64];
    __shared__ float hid[32];
    int t = threadIdx.x;
    int o = t & 63, p = t >> 6;
    int b = blockIdx.x;
    const _Float16* hb = hhi + (size_t)b*M_*H_;
    const _Float16* lb = hlo + (size_t)b*M_*H_;
    float s = 0.f;
    for (int m = p; m < M_; m += 4)
        s += (float)hb[(size_t)m*64 + o] + (float)lb[(size_t)m*64 + o];
    part[p][o] = s;
    __syncthreads();
    if (t < 64) g[t] = (part[0][t] + part[1][t] + part[2][t] + part[3][t]) * (1.f/M_);
    __syncthreads();
    if (t < 32) {
        float a = b1[t];
        for (int f = 0; f < 64; ++f) a += g[f] * w1[f*32 + t];
        hid[t] = fmaxf(a, 0.f);
    }
    __syncthreads();
    if (t == 0) {
        float a = b2[0];
        for (int f = 0; f < 32; ++f) a += hid[f] * w2[f];
        out[b] = a;
    }
}

extern "C" void kernel_launch(void* const* d_in, const int* in_sizes, int n_in,
                              void* d_out, int out_size, void* d_ws, size_t ws_size,
                              hipStream_t stream)
{
    (void)in_sizes; (void)n_in; (void)out_size; (void)ws_size;
    const float* x      = (const float*)d_in[0];
    const float* enc_w1 = (const float*)d_in[2];
    const float* enc_b1 = (const float*)d_in[3];
    const float* enc_w2 = (const float*)d_in[4];
    const float* enc_b2 = (const float*)d_in[5];
    const float* ec1_w1 = (const float*)d_in[6];
    const float* ec1_b1 = (const float*)d_in[7];
    const float* ec1_w2 = (const float*)d_in[8];
    const float* ec1_b2 = (const float*)d_in[9];
    const float* ec2_w1 = (const float*)d_in[10];
    const float* ec2_b1 = (const float*)d_in[11];
    const float* ec2_w2 = (const float*)d_in[12];
    const float* ec2_b2 = (const float*)d_in[13];
    const float* out_w1 = (const float*)d_in[14];
    const float* out_b1 = (const float*)d_in[15];
    const float* out_w2 = (const float*)d_in[16];
    const float* out_b2 = (const float*)d_in[17];

    // ws layout, 34.25 MB, NO aliasing (hidden state lives only as f16 split):
    char* ws = (char*)d_ws;
    _Float16*       hhi = (_Float16*)(ws);                               //  8 MB
    _Float16*       hlo = (_Float16*)(ws + (size_t)N_*64*2);             //  8 MB
    float*          A   = (float*)   (ws + (size_t)N_*64*4);             // 16 MB
    unsigned short* idx = (unsigned short*)(ws + (size_t)N_*64*8);       //  2 MB
    float*          sq  = (float*)   (ws + (size_t)N_*64*8 + (size_t)N_*16*2); // 256 KB

    enc_kernel<<<N_/256, 256, 0, stream>>>(x, enc_w1, enc_b1, enc_w2, enc_b2,
                                           ec1_w1, hhi, hlo, sq, A);
    knn_kernel <<<B_*16, 256, 0, stream>>>(hhi, hlo, sq, idx);
    edge_kernel<<<N_/64, 256, 0, stream>>>(hhi, hlo, A, idx,
                                           ec1_w1, ec1_b1, ec1_w2, ec1_b2);
    prep2_kernel<<<N_/256, 256, 0, stream>>>(hhi, hlo, ec2_w1, A, sq);
    knn_kernel <<<B_*16, 256, 0, stream>>>(hhi, hlo, sq, idx);
    edge_kernel<<<N_/64, 256, 0, stream>>>(hhi, hlo, A, idx,
                                           ec2_w1, ec2_b1, ec2_w2, ec2_b2);
    pool_kernel<<<B_, 256, 0, stream>>>(hhi, hlo, out_w1, out_b1, out_w2, out_b2,
                                        (float*)d_out);
}

// Round 15
// 421.771 us; speedup vs baseline: 1.3034x; 1.3034x over previous
//
#include <hip/hip_runtime.h>
#include <math.h>

#define B_ 64
#define M_ 1024
#define H_ 64
#define N_ (B_*M_)   // 65536

typedef _Float16 half8 __attribute__((ext_vector_type(8)));
typedef float  floatx4 __attribute__((ext_vector_type(4)));

#define MFMA16(a,b,c) __builtin_amdgcn_mfma_f32_16x16x32_f16(a,b,c,0,0,0)
#define MED3(a,b,c)   __builtin_amdgcn_fmed3f(a,b,c)

// ---- encoder: hhi/hlo = f16-split(relu MLP(x)) ----
__global__ __launch_bounds__(256) void enc_kernel(
    const float* __restrict__ x,     // [N,4]
    const float* __restrict__ w1,    // [4,32]
    const float* __restrict__ b1,    // [32]
    const float* __restrict__ w2,    // [32,64]
    const float* __restrict__ b2,    // [64]
    _Float16* __restrict__ hhi,      // [N,64]
    _Float16* __restrict__ hlo)      // [N,64]
{
    __shared__ float sw1[4*32];
    __shared__ float sb1[32];
    __shared__ float sw2[32*64];
    __shared__ float sb2[64];
    int t = threadIdx.x;
    for (int i = t; i < 128; i += 256) sw1[i] = w1[i];
    if (t < 32) sb1[t] = b1[t];
    for (int i = t; i < 2048; i += 256) sw2[i] = w2[i];
    if (t < 64) sb2[t] = b2[t];
    __syncthreads();
    int n = blockIdx.x * 256 + t;
    float4 xv = *(const float4*)(x + (size_t)n*4);
    float hid[32];
    #pragma unroll
    for (int o = 0; o < 32; ++o) {
        float a = sb1[o] + xv.x*sw1[0*32+o] + xv.y*sw1[1*32+o]
                        + xv.z*sw1[2*32+o] + xv.w*sw1[3*32+o];
        hid[o] = fmaxf(a, 0.f);
    }
    #pragma unroll 4
    for (int oc = 0; oc < 16; ++oc) {
        float4 acc = make_float4(sb2[oc*4+0], sb2[oc*4+1], sb2[oc*4+2], sb2[oc*4+3]);
        #pragma unroll
        for (int f = 0; f < 32; ++f) {
            float4 w = *(const float4*)(sw2 + f*64 + oc*4);
            float hv_ = hid[f];
            acc.x += hv_*w.x; acc.y += hv_*w.y; acc.z += hv_*w.z; acc.w += hv_*w.w;
        }
        acc.x = fmaxf(acc.x,0.f); acc.y = fmaxf(acc.y,0.f);
        acc.z = fmaxf(acc.z,0.f); acc.w = fmaxf(acc.w,0.f);
        union { _Float16 f[4]; uint2 u; } Hh, Hl;
        Hh.f[0]=(_Float16)acc.x; Hh.f[1]=(_Float16)acc.y;
        Hh.f[2]=(_Float16)acc.z; Hh.f[3]=(_Float16)acc.w;
        Hl.f[0]=(_Float16)(acc.x-(float)Hh.f[0]); Hl.f[1]=(_Float16)(acc.y-(float)Hh.f[1]);
        Hl.f[2]=(_Float16)(acc.z-(float)Hh.f[2]); Hl.f[3]=(_Float16)(acc.w-(float)Hh.f[3]);
        *(uint2*)(hhi + (size_t)n*64 + oc*4) = Hh.u;
        *(uint2*)(hlo + (size_t)n*64 + oc*4) = Hl.u;
    }
}

// ---- aprep (both layers): MFMA A = h @ W1b, shuffle-reduced sq ----
// Clone of edge phase-1 (proven): wave = 16 nodes, 24 MFMAs.
__global__ __launch_bounds__(256) void aprep_kernel(
    const _Float16* __restrict__ hhi,
    const _Float16* __restrict__ hlo,
    const float* __restrict__ ecw1,   // [128,64]; rows 64.. = W1b
    float* __restrict__ A,            // [N,64]
    float* __restrict__ sq)           // [N]
{
    __shared__ __align__(16) _Float16 wbf[16*64*8];  // W1b B-frags f16-split (16 KB)
    int t = threadIdx.x;
    for (int u = t; u < 512; u += 256) {
        int ulane = u & 63, nt = u >> 7, ks = (u >> 6) & 1;
        int n = nt*16 + (ulane & 15);
        int kbase = ks*32 + ((ulane >> 4) * 8);
        int fh = (((nt*2+ks)*2+0)*64 + ulane)*8;
        int fl = (((nt*2+ks)*2+1)*64 + ulane)*8;
        #pragma unroll
        for (int j = 0; j < 8; ++j) {
            int k = kbase + j;
            float vb = ecw1[4096 + k*64 + n];
            _Float16 bh = (_Float16)vb;
            wbf[fh+j] = bh;
            wbf[fl+j] = (_Float16)(vb - (float)bh);
        }
    }
    __syncthreads();
    int lane = t & 63, wid = t >> 6;
    int m16 = lane & 15, gid = lane >> 4;
    int koct = gid*8, crow = gid*4;
    int bi = blockIdx.x;
    int g  = (bi & 7) | ((bi >> 7) << 3);    // XCD swizzle
    int qt = (bi >> 3) & 15;
    int i0 = g*M_ + qt*64 + wid*16;
    half8 Hh[2], Hl[2];
    #pragma unroll
    for (int ks = 0; ks < 2; ++ks) {
        Hh[ks] = *(const half8*)(hhi + (size_t)(i0+m16)*64 + ks*32 + koct);
        Hl[ks] = *(const half8*)(hlo + (size_t)(i0+m16)*64 + ks*32 + koct);
    }
    // sq: per-lane partial over 16 features, combine the 4 gid lanes
    float s = 0.f;
    #pragma unroll
    for (int ks = 0; ks < 2; ++ks)
        #pragma unroll
        for (int j = 0; j < 8; ++j) {
            float v = (float)Hh[ks][j] + (float)Hl[ks][j];
            s += v*v;
        }
    s += __shfl_xor(s, 16, 64);
    s += __shfl_xor(s, 32, 64);
    if (gid == 0) sq[i0 + m16] = s;
    // A = h @ W1b via f16-split MFMA
    #pragma unroll
    for (int nt = 0; nt < 4; ++nt) {
        floatx4 acc = {0.f, 0.f, 0.f, 0.f};
        #pragma unroll
        for (int ks = 0; ks < 2; ++ks) {
            half8 wh = *(const half8*)&wbf[(((nt*2+ks)*2+0)*64+lane)*8];
            half8 wl = *(const half8*)&wbf[(((nt*2+ks)*2+1)*64+lane)*8];
            acc = MFMA16(Hh[ks], wh, acc);
            acc = MFMA16(Hh[ks], wl, acc);
            acc = MFMA16(Hl[ks], wh, acc);
        }
        #pragma unroll
        for (int r = 0; r < 4; ++r)
            A[(size_t)(i0 + crow + r)*64 + nt*16 + m16] = acc[r];
    }
}

// ---- kNN v11 (R13, proven 74.7us): LDS D-tile, packed keys folded into acc ----
__global__ __launch_bounds__(256) void knn_kernel(
    const _Float16* __restrict__ hhi,
    const _Float16* __restrict__ hlo,
    const float* __restrict__ sqg,
    unsigned short* __restrict__ knn)    // [N,16]
{
    __shared__ float D[4][64*33];         // per-wave 64q x 32c key tile (33.8 KB)
    __shared__ float sqS[1024];
    int t = threadIdx.x, lane = t & 63, w = t >> 6;
    int bi = blockIdx.x;
    int g  = (bi & 7) | ((bi >> 7) << 3);  // 16 blocks/graph share bi%8 -> same XCD L2
    int qt = (bi >> 3) & 15;
    const _Float16* hhig = hhi + (size_t)g*M_*64;
    const _Float16* hlog = hlo + (size_t)g*M_*64;
    const float*    sqb  = sqg + (size_t)g*M_;
    ((float4*)sqS)[t] = ((const float4*)sqb)[t];   // 4 KB

    int m16  = lane & 15;
    int koct = (lane >> 4) * 8;
    int crow = (lane >> 4) * 4;      // C/D: col=lane&15, row=(lane>>4)*4+reg
    half8 Ahi[4][2], Alo[4][2];
    #pragma unroll
    for (int rb = 0; rb < 4; ++rb) {
        const _Float16* ph = hhig + (size_t)(qt*64 + rb*16 + m16)*64;
        const _Float16* pl = hlog + (size_t)(qt*64 + rb*16 + m16)*64;
        Ahi[rb][0] = *(const half8*)(ph + koct);
        Ahi[rb][1] = *(const half8*)(ph + 32 + koct);
        Alo[rb][0] = *(const half8*)(pl + koct);
        Alo[rb][1] = *(const half8*)(pl + 32 + koct);
    }
    #pragma unroll
    for (int rb = 0; rb < 4; ++rb)
        #pragma unroll
        for (int p = 0; p < 2; ++p)
            #pragma unroll
            for (int j = 0; j < 8; ++j) {
                Ahi[rb][p][j] = Ahi[rb][p][j] * (_Float16)-2.0f;
                Alo[rb][p][j] = Alo[rb][p][j] * (_Float16)-2.0f;
            }
    __syncthreads();                 // sqS ready
    float c1r[4][4];
    #pragma unroll
    for (int rb = 0; rb < 4; ++rb)
        #pragma unroll
        for (int r = 0; r < 4; ++r)
            c1r[rb][r] = 1.f + sqS[qt*64 + rb*16 + crow + r];

    float* Dw = D[w];
    float bd[16];
    #pragma unroll
    for (int k = 0; k < 16; ++k) bd[k] = INFINITY;
    int cand0 = w*256;
    int selfc_all = qt*64 + lane;

    #pragma unroll
    for (int cc = 0; cc < 8; ++cc) {      // 8 chunks of 32 candidates (static!)
        int cbase = cand0 + cc*32;
        half8 Bhi[2][2], Blo[2][2];
        #pragma unroll
        for (int cb = 0; cb < 2; ++cb) {
            const _Float16* ph = hhig + (size_t)(cbase + cb*16 + m16)*64;
            const _Float16* pl = hlog + (size_t)(cbase + cb*16 + m16)*64;
            Bhi[cb][0] = *(const half8*)(ph + koct);
            Bhi[cb][1] = *(const half8*)(ph + 32 + koct);
            Blo[cb][0] = *(const half8*)(pl + koct);
            Blo[cb][1] = *(const half8*)(pl + 32 + koct);
        }
        #pragma unroll
        for (int rb = 0; rb < 4; ++rb) {
            #pragma unroll
            for (int cb = 0; cb < 2; ++cb) {
                float sqj = sqS[cbase + cb*16 + m16];
                floatx4 acc = {c1r[rb][0]+sqj, c1r[rb][1]+sqj,
                               c1r[rb][2]+sqj, c1r[rb][3]+sqj};
                acc = MFMA16(Ahi[rb][0], Bhi[cb][0], acc);
                acc = MFMA16(Ahi[rb][1], Bhi[cb][1], acc);
                acc = MFMA16(Ahi[rb][0], Blo[cb][0], acc);
                acc = MFMA16(Ahi[rb][1], Blo[cb][1], acc);
                acc = MFMA16(Alo[rb][0], Bhi[cb][0], acc);
                acc = MFMA16(Alo[rb][1], Bhi[cb][1], acc);
                #pragma unroll
                for (int r = 0; r < 4; ++r)
                    Dw[(rb*16 + crow + r)*33 + cb*16 + m16] = acc[r];
            }
        }
        const float* drow = Dw + lane*33;
        int selfc = selfc_all - cbase;       // in [0,32) iff self in this chunk
        #pragma unroll
        for (int c8 = 0; c8 < 4; ++c8) {
            float sv[8];
            #pragma unroll
            for (int j = 0; j < 8; ++j) sv[j] = drow[c8*8 + j];
            #pragma unroll
            for (int j = 0; j < 8; ++j) {
                int c = c8*8 + j;
                unsigned kb = (__float_as_uint(sv[j]) & 0xFFFFFC00u)
                            | (unsigned)(cbase + c);
                float fk = __uint_as_float(kb);
                if (c == selfc) fk = INFINITY;
                float nb0 = fminf(bd[0], fk);
                #pragma unroll
                for (int k = 15; k >= 1; --k) bd[k] = MED3(fk, bd[k-1], bd[k]);
                bd[0] = nb0;
            }
        }
    }

    __syncthreads();
    float* md = &D[0][0];            // alias as md[64][65]
    #pragma unroll
    for (int k = 0; k < 16; ++k) md[lane*65 + w*16 + k] = bd[k];
    __syncthreads();
    if (w == 0) {
        float b2[16];
        #pragma unroll
        for (int k = 0; k < 16; ++k) b2[k] = INFINITY;
        const float* mrow = md + lane*65;
        #pragma unroll
        for (int c8 = 0; c8 < 8; ++c8) {
            float sv[8];
            #pragma unroll
            for (int j = 0; j < 8; ++j) sv[j] = mrow[c8*8 + j];
            #pragma unroll
            for (int j = 0; j < 8; ++j) {
                float s = sv[j];
                float nb0 = fminf(b2[0], s);
                #pragma unroll
                for (int k = 15; k >= 1; --k) b2[k] = MED3(s, b2[k-1], b2[k]);
                b2[0] = nb0;
            }
        }
        union { unsigned short us[16]; uint4 v4[2]; } o;
        #pragma unroll
        for (int k = 0; k < 16; ++k)
            o.us[k] = (unsigned short)(__float_as_uint(b2[k]) & 1023u);
        size_t gq = (size_t)g*M_ + qt*64 + lane;
        uint4* dst = (uint4*)(knn + gq*16);
        dst[0] = o.v4[0];
        dst[1] = o.v4[1];
    }
}

// ---- EdgeConv v5 (R13, proven): MFMA, f16 state in/out ----
__global__ __launch_bounds__(256) void edge_kernel(
    _Float16* __restrict__ hhi,      // [N,64] in/out (own rows read before written)
    _Float16* __restrict__ hlo,      // [N,64] in/out
    const float* __restrict__ A,     // [N,64]
    const unsigned short* __restrict__ knn, // [N,16] local idx
    const float* __restrict__ w1,    // [128,64]
    const float* __restrict__ b1,    // [64]
    const float* __restrict__ w2,    // [64,64]
    const float* __restrict__ b2)    // [64]
{
    __shared__ __align__(16) _Float16 wdf[16*64*8];   // Wd B-frags (16 KB)
    __shared__ __align__(16) _Float16 w2f[16*64*8];   // W2 B-frags (16 KB) -> Cs after
    float* CsB = (float*)w2f;                          // Cs[4][16][64] alias
    int t = threadIdx.x;
    for (int u = t; u < 512; u += 256) {
        int ulane = u & 63, nt = u >> 7, ks = (u >> 6) & 1;
        int n = nt*16 + (ulane & 15);
        int kbase = ks*32 + ((ulane >> 4) * 8);
        int fh = (((nt*2+ks)*2+0)*64 + ulane)*8;
        int fl = (((nt*2+ks)*2+1)*64 + ulane)*8;
        #pragma unroll
        for (int j = 0; j < 8; ++j) {
            int k = kbase + j;
            float vd = w1[k*64+n] - w1[4096 + k*64+n];
            _Float16 dh = (_Float16)vd;
            wdf[fh+j] = dh;
            wdf[fl+j] = (_Float16)(vd - (float)dh);
            float v2 = w2[k*64+n];
            _Float16 h2 = (_Float16)v2;
            w2f[fh+j] = h2;
            w2f[fl+j] = (_Float16)(v2 - (float)h2);
        }
    }
    __syncthreads();
    int lane = t & 63, wid = t >> 6;
    int m16 = lane & 15, gid = lane >> 4;
    int koct = gid*8, crow = gid*4;
    int bi = blockIdx.x;
    int g  = (bi & 7) | ((bi >> 7) << 3);    // XCD swizzle
    int qt = (bi >> 3) & 15;
    int i0 = g*M_ + qt*64 + wid*16;
    const float* Ab = A + (size_t)g*M_*H_;

    half8 W2r[4][2][2];
    #pragma unroll
    for (int nt = 0; nt < 4; ++nt)
        #pragma unroll
        for (int ks = 0; ks < 2; ++ks)
            #pragma unroll
            for (int p = 0; p < 2; ++p)
                W2r[nt][ks][p] = *(const half8*)&w2f[(((nt*2+ks)*2+p)*64+lane)*8];

    float b1v[4];
    #pragma unroll
    for (int nt = 0; nt < 4; ++nt) b1v[nt] = b1[nt*16+m16];
    float b2v = b2[gid*16+m16];
    __syncthreads();   // all waves done reading w2f -> safe to overwrite with Cs

    half8 Hh[2], Hl[2];
    #pragma unroll
    for (int ks = 0; ks < 2; ++ks) {
        Hh[ks] = *(const half8*)(hhi + (size_t)(i0+m16)*64 + ks*32 + koct);
        Hl[ks] = *(const half8*)(hlo + (size_t)(i0+m16)*64 + ks*32 + koct);
    }
    #pragma unroll
    for (int nt = 0; nt < 4; ++nt) {
        floatx4 acc = {b1v[nt], b1v[nt], b1v[nt], b1v[nt]};
        #pragma unroll
        for (int ks = 0; ks < 2; ++ks) {
            half8 wh = *(const half8*)&wdf[(((nt*2+ks)*2+0)*64+lane)*8];
            half8 wl = *(const half8*)&wdf[(((nt*2+ks)*2+1)*64+lane)*8];
            acc = MFMA16(Hh[ks], wh, acc);
            acc = MFMA16(Hh[ks], wl, acc);
            acc = MFMA16(Hl[ks], wh, acc);
        }
        #pragma unroll
        for (int r = 0; r < 4; ++r)
            CsB[((wid*16) + crow + r)*64 + nt*16 + m16] = acc[r];
    }
    __syncthreads();

    const unsigned short* knb = knn + (size_t)i0*16;
    #pragma unroll 2
    for (int nn = 0; nn < 16; ++nn) {
        int j = knb[nn*16 + m16];
        const float* Ap = Ab + (size_t)j*64;
        half8 Mh[2], Ml[2];
        #pragma unroll
        for (int ks = 0; ks < 2; ++ks) {
            float4 a0 = *(const float4*)(Ap + ks*32 + koct);
            float4 a1 = *(const float4*)(Ap + ks*32 + koct + 4);
            const float* cp = &CsB[(wid*16 + nn)*64 + ks*32 + koct];
            float4 c0 = *(const float4*)cp;
            float4 c1 = *(const float4*)(cp+4);
            float mv[8] = {
                fmaxf(a0.x+c0.x,0.f), fmaxf(a0.y+c0.y,0.f),
                fmaxf(a0.z+c0.z,0.f), fmaxf(a0.w+c0.w,0.f),
                fmaxf(a1.x+c1.x,0.f), fmaxf(a1.y+c1.y,0.f),
                fmaxf(a1.z+c1.z,0.f), fmaxf(a1.w+c1.w,0.f)};
            #pragma unroll
            for (int jj = 0; jj < 8; ++jj) {
                _Float16 hi = (_Float16)mv[jj];
                Mh[ks][jj] = hi;
                Ml[ks][jj] = (_Float16)(mv[jj]-(float)hi);
            }
        }
        floatx4 acc[4];
        #pragma unroll
        for (int nt = 0; nt < 4; ++nt) {
            acc[nt] = (floatx4){0.f,0.f,0.f,0.f};
            #pragma unroll
            for (int ks = 0; ks < 2; ++ks) {
                acc[nt] = MFMA16(Mh[ks], W2r[nt][ks][0], acc[nt]);
                acc[nt] = MFMA16(Mh[ks], W2r[nt][ks][1], acc[nt]);
                acc[nt] = MFMA16(Ml[ks], W2r[nt][ks][0], acc[nt]);
            }
        }
        float om[4];
        #pragma unroll
        for (int nt = 0; nt < 4; ++nt) {
            float mr = fmaxf(fmaxf(acc[nt][0], acc[nt][1]),
                             fmaxf(acc[nt][2], acc[nt][3]));
            mr = fmaxf(mr, __shfl_xor(mr, 16, 64));
            mr = fmaxf(mr, __shfl_xor(mr, 32, 64));
            om[nt] = mr;
        }
        float val = (gid == 0) ? om[0] : (gid == 1) ? om[1]
                  : (gid == 2) ? om[2] : om[3];
        float ov = val + b2v;                      // h_out[i0+nn][lane]
        _Float16 oh = (_Float16)ov;
        _Float16 ol = (_Float16)(ov - (float)oh);
        hhi[(size_t)(i0+nn)*64 + lane] = oh;
        hlo[(size_t)(i0+nn)*64 + lane] = ol;
    }
}

// ---- mean-pool + output MLP (reads hhi+hlo) ----
__global__ __launch_bounds__(256) void pool_kernel(
    const _Float16* __restrict__ hhi,
    const _Float16* __restrict__ hlo,
    const float* __restrict__ w1,   // [64,32]
    const float* __restrict__ b1,   // [32]
    const float* __restrict__ w2,   // [32,1]
    const float* __restrict__ b2,   // [1]
    float* __restrict__ out)        // [B]
{
    __shared__ float part[4][64];
    __shared__ float g[64];
    __shared__ float hid[32];
    int t = threadIdx.x;
    int o = t & 63, p = t >> 6;
    int b = blockIdx.x;
    const _Float16* hb = hhi + (size_t)b*M_*H_;
    const _Float16* lb = hlo + (size_t)b*M_*H_;
    float s = 0.f;
    for (int m = p; m < M_; m += 4)
        s += (float)hb[(size_t)m*64 + o] + (float)lb[(size_t)m*64 + o];
    part[p][o] = s;
    __syncthreads();
    if (t < 64) g[t] = (part[0][t] + part[1][t] + part[2][t] + part[3][t]) * (1.f/M_);
    __syncthreads();
    if (t < 32) {
        float a = b1[t];
        for (int f = 0; f < 64; ++f) a += g[f] * w1[f*32 + t];
        hid[t] = fmaxf(a, 0.f);
    }
    __syncthreads();
    if (t == 0) {
        float a = b2[0];
        for (int f = 0; f < 32; ++f) a += hid[f] * w2[f];
        out[b] = a;
    }
}

extern "C" void kernel_launch(void* const* d_in, const int* in_sizes, int n_in,
                              void* d_out, int out_size, void* d_ws, size_t ws_size,
                              hipStream_t stream)
{
    (void)in_sizes; (void)n_in; (void)out_size; (void)ws_size;
    const float* x      = (const float*)d_in[0];
    const float* enc_w1 = (const float*)d_in[2];
    const float* enc_b1 = (const float*)d_in[3];
    const float* enc_w2 = (const float*)d_in[4];
    const float* enc_b2 = (const float*)d_in[5];
    const float* ec1_w1 = (const float*)d_in[6];
    const float* ec1_b1 = (const float*)d_in[7];
    const float* ec1_w2 = (const float*)d_in[8];
    const float* ec1_b2 = (const float*)d_in[9];
    const float* ec2_w1 = (const float*)d_in[10];
    const float* ec2_b1 = (const float*)d_in[11];
    const float* ec2_w2 = (const float*)d_in[12];
    const float* ec2_b2 = (const float*)d_in[13];
    const float* out_w1 = (const float*)d_in[14];
    const float* out_b1 = (const float*)d_in[15];
    const float* out_w2 = (const float*)d_in[16];
    const float* out_b2 = (const float*)d_in[17];

    // ws layout, 34.25 MB, NO aliasing (hidden state lives only as f16 split):
    char* ws = (char*)d_ws;
    _Float16*       hhi = (_Float16*)(ws);                               //  8 MB
    _Float16*       hlo = (_Float16*)(ws + (size_t)N_*64*2);             //  8 MB
    float*          A   = (float*)   (ws + (size_t)N_*64*4);             // 16 MB
    unsigned short* idx = (unsigned short*)(ws + (size_t)N_*64*8);       //  2 MB
    float*          sq  = (float*)   (ws + (size_t)N_*64*8 + (size_t)N_*16*2); // 256 KB

    // 8 dispatches: enc, aprep1, knn, edge1, aprep2, knn, edge2, pool
    enc_kernel  <<<N_/256, 256, 0, stream>>>(x, enc_w1, enc_b1, enc_w2, enc_b2,
                                             hhi, hlo);
    aprep_kernel<<<N_/64, 256, 0, stream>>>(hhi, hlo, ec1_w1, A, sq);
    knn_kernel  <<<B_*16, 256, 0, stream>>>(hhi, hlo, sq, idx);
    edge_kernel <<<N_/64, 256, 0, stream>>>(hhi, hlo, A, idx,
                                            ec1_w1, ec1_b1, ec1_w2, ec1_b2);
    aprep_kernel<<<N_/64, 256, 0, stream>>>(hhi, hlo, ec2_w1, A, sq);
    knn_kernel  <<<B_*16, 256, 0, stream>>>(hhi, hlo, sq, idx);
    edge_kernel <<<N_/64, 256, 0, stream>>>(hhi, hlo, A, idx,
                                            ec2_w1, ec2_b1, ec2_w2, ec2_b2);
    pool_kernel <<<B_, 256, 0, stream>>>(hhi, hlo, out_w1, out_b1, out_w2, out_b2,
                                         (float*)d_out);
}